// Round 5
// baseline (194.673 us; speedup 1.0000x reference)
//
#include <hip/hip_runtime.h>
#include <math.h>

#define NN 64      // nodes per graph
#define HH 128     // hidden channels
#define NBB 8      // bessel basis
#define TT 32      // time embedding dim
#define BB 64      // batch

typedef __attribute__((ext_vector_type(8))) short short8;
typedef __attribute__((ext_vector_type(4))) float f32x4;
typedef __attribute__((ext_vector_type(2))) float f32x2;

__device__ __forceinline__ float silu_f(float x) {
  return x * __builtin_amdgcn_rcpf(1.0f + __expf(-x));
}

__device__ __forceinline__ unsigned short f2bf(float x) {
  union { float f; unsigned u; } v; v.f = x;
  unsigned r = v.u + 0x7FFFu + ((v.u >> 16) & 1u);   // round-to-nearest-even
  return (unsigned short)(r >> 16);
}

// One block per graph b: pack a 512-elem slice of Wr2 -> bf16 B-frag order,
// compute h[b,n,:] = emb[z[b,n],:] + gf[b,:] @ Wt.
__global__ __launch_bounds__(256) void k_init(
    const float* __restrict__ emb, const int* __restrict__ z,
    const float* __restrict__ gf, const float* __restrict__ Wt,
    const float* __restrict__ Wr2, float* __restrict__ h,
    unsigned short* __restrict__ Wr2p) {
  __shared__ float tvec[HH];
  __shared__ int sz[NN];
  int b = blockIdx.x, tid = threadIdx.x;
#pragma unroll
  for (int ii = 0; ii < 2; ++ii) {        // Wr2 pack: dst[(((l*4+kt)*128+n)*4+q)*8+j]
    int idx = b * 512 + ii * 256 + tid;
    int l = idx >> 14, k = (idx >> 7) & 127, n = idx & 127;
    int kt = k >> 5, q = (k >> 3) & 3, j = k & 7;
    Wr2p[((((l * 4 + kt) * 128 + n) * 4 + q) * 8) + j] = f2bf(Wr2[idx]);
  }
  if (tid < NN) sz[tid] = z[b * NN + tid];
  if (tid < HH) {
    float acc = 0.f;
#pragma unroll
    for (int k = 0; k < TT; ++k) acc += gf[b * TT + k] * Wt[k * HH + tid];
    tvec[tid] = acc;
  }
  __syncthreads();
  for (int i = tid; i < NN * HH; i += 256) {
    int n = i >> 7, c = i & 127;
    h[(size_t)b * NN * HH + i] = emb[sz[n] * HH + c] + tvec[c];
  }
}

// One block (256 thr = 4 waves) per (b, receiver r).
// A: rb/u (flat over 256 threads, transposed LDS layout -> conflict-free).
// B: S = silu(rb@Wr1) -> bf16 LDS. GEMM: w = S@Wr2 via mfma.
// Epilogue: m0 = w*h[snd], weight by u, quad-reduce, write a0a1[blk][c][4].
__global__ __launch_bounds__(256) void k_layer(
    const float* __restrict__ pos,
    const float* __restrict__ hin,
    float* __restrict__ a0a1,
    const float* __restrict__ Wr1, const unsigned short* __restrict__ Wr2p,
    int l) {
  __shared__ __align__(16) unsigned short sh_S[NN][136];   // +8 pad: conflict-free frags
  __shared__ __align__(16) float sh_rb[NBB][NN];           // k-major: stride-4B writes
  __shared__ __align__(16) float sh_u[3][NN];

  int blk = blockIdx.x;          // b*NN + r
  int b = blk >> 6, r = blk & 63;
  int tid = threadIdx.x;
  int w = tid >> 6, lane = tid & 63;

  // ---- Stage A: geometry + bessel, flat over all 256 threads ----
  {
    int s = tid & 63, ksel = tid >> 6;    // each thread: one sender, two basis terms
    const float* pb = pos + b * NN * 3;
    float dx = pb[r * 3 + 0] - pb[s * 3 + 0];
    float dy = pb[r * 3 + 1] - pb[s * 3 + 1];
    float dz = pb[r * 3 + 2] - pb[s * 3 + 2];
    float rr = sqrtf(dx * dx + dy * dy + dz * dz + 1e-12f);
    float inv = __builtin_amdgcn_rcpf(rr);
    if (ksel == 0) {
      sh_u[0][s] = dx * inv; sh_u[1][s] = dy * inv; sh_u[2][s] = dz * inv;
    }
    const float PI_OVER_5 = 0.628318530717958647692f;
    float fc = (s != r && rr < 5.0f) ? 0.5f * (__cosf(PI_OVER_5 * rr) + 1.0f) : 0.0f;
    float base = PI_OVER_5 * rr;
    float sc = inv * fc;
    sh_rb[ksel * 2 + 0][s] = __sinf((float)(ksel * 2 + 1) * base) * sc;
    sh_rb[ksel * 2 + 1][s] = __sinf((float)(ksel * 2 + 2) * base) * sc;
  }
  __syncthreads();

  // ---- Stage B: S[s][c] = silu(rb[s]@Wr1[:,c]) -> bf16; wave w: s in [w*16, w*16+16) ----
  {
    const float* Wr1l = Wr1 + l * NBB * HH;
    int c0 = 2 * lane;
    float wc0[NBB], wc1[NBB];
#pragma unroll
    for (int k = 0; k < NBB; ++k) { wc0[k] = Wr1l[k * HH + c0]; wc1[k] = Wr1l[k * HH + c0 + 1]; }
    int sbase = w * 16;
#pragma unroll 4
    for (int si = 0; si < 16; ++si) {
      int s = sbase + si;
      float rbv[NBB];
#pragma unroll
      for (int k = 0; k < NBB; ++k) rbv[k] = sh_rb[k][s];   // LDS broadcast (free)
      float a0 = 0.f, a1 = 0.f;
#pragma unroll
      for (int k = 0; k < NBB; ++k) { a0 += rbv[k] * wc0[k]; a1 += rbv[k] * wc1[k]; }
      unsigned packed = (unsigned)f2bf(silu_f(a0)) | ((unsigned)f2bf(silu_f(a1)) << 16);
      *(unsigned*)&sh_S[s][c0] = packed;
    }
  }
  __syncthreads();

  // ---- GEMM + message epilogue (wave w owns c in [w*32, w*32+32)) ----
  const unsigned short* Bbase = Wr2p + l * 16384;
  int nlo = lane & 15, quad = lane >> 4;
  short8 bfr[4][2];
#pragma unroll
  for (int kt = 0; kt < 4; ++kt)
#pragma unroll
    for (int nt = 0; nt < 2; ++nt) {
      int c = w * 32 + nt * 16 + nlo;
      bfr[kt][nt] = *(const short8*)&Bbase[((kt * 128 + c) * 4 + quad) * 8];
    }
  float acc0[2] = {0.f, 0.f};
  float a1x[2] = {0.f, 0.f};
  float a1y[2] = {0.f, 0.f};
  float a1z[2] = {0.f, 0.f};
  const float* hb = hin + (size_t)b * NN * HH;

#pragma unroll
  for (int mt = 0; mt < 4; ++mt) {
    short8 afr[4];
    int s_a = mt * 16 + nlo;
#pragma unroll
    for (int kt = 0; kt < 4; ++kt)
      afr[kt] = *(const short8*)&sh_S[s_a][kt * 32 + quad * 8];
    float ux[4], uy[4], uz[4];
#pragma unroll
    for (int reg = 0; reg < 4; ++reg) {
      int s = mt * 16 + quad * 4 + reg;
      ux[reg] = sh_u[0][s]; uy[reg] = sh_u[1][s]; uz[reg] = sh_u[2][s];
    }
#pragma unroll
    for (int nt = 0; nt < 2; ++nt) {
      int c = w * 32 + nt * 16 + nlo;
      f32x4 C = {0.f, 0.f, 0.f, 0.f};
#pragma unroll
      for (int kt = 0; kt < 4; ++kt)
        C = __builtin_amdgcn_mfma_f32_16x16x32_bf16(afr[kt], bfr[kt][nt], C, 0, 0, 0);
#pragma unroll
      for (int reg = 0; reg < 4; ++reg) {
        int s = mt * 16 + quad * 4 + reg;
        float m0 = C[reg] * hb[s * HH + c];
        acc0[nt] += m0;
        a1x[nt] += m0 * ux[reg];
        a1y[nt] += m0 * uy[reg];
        a1z[nt] += m0 * uz[reg];
      }
    }
  }

  // quad-reduce -> global a0a1[blk][c][{a0,a1x,a1y,a1z}]
  const float invAvg = 1.0f / 63.0f;
#pragma unroll
  for (int nt = 0; nt < 2; ++nt) {
    float q0 = acc0[nt], q1 = a1x[nt], q2 = a1y[nt], q3 = a1z[nt];
    q0 += __shfl_xor(q0, 16); q0 += __shfl_xor(q0, 32);
    q1 += __shfl_xor(q1, 16); q1 += __shfl_xor(q1, 32);
    q2 += __shfl_xor(q2, 16); q2 += __shfl_xor(q2, 32);
    q3 += __shfl_xor(q3, 16); q3 += __shfl_xor(q3, 32);
    if (quad == 0) {
      int c = w * 32 + nt * 16 + nlo;
      f32x4 val = {q0 * invAvg, q1 * invAvg, q2 * invAvg, q3 * invAvg};
      *(f32x4*)&a0a1[((size_t)blk * HH + c) * 4] = val;
    }
  }
}

// Batched node update, 16 rows/block: hout = hin + a0@Wul ; v = a1@Wml (write).
__global__ __launch_bounds__(256) void k_update(
    const float* __restrict__ a0a1, const float* __restrict__ hin,
    float* __restrict__ hout, float* __restrict__ v,
    const float* __restrict__ Wul, const float* __restrict__ Wml) {
  __shared__ __align__(16) f32x4 sh_a[16][HH];    // 32 KB
  int tid = threadIdx.x;
  int row0 = blockIdx.x * 16;
  const f32x4* src = (const f32x4*)(a0a1 + (size_t)row0 * HH * 4);
  for (int i = tid; i < 16 * HH; i += 256) sh_a[i >> 7][i & 127] = src[i];
  __syncthreads();
  int c4 = (tid & 31) * 4;
  int rg = tid >> 5;                     // rows rg*2, rg*2+1
  f32x4 hA = {0,0,0,0}, hB = {0,0,0,0};
  f32x4 xA = {0,0,0,0}, xB = {0,0,0,0};
  f32x4 yA = {0,0,0,0}, yB = {0,0,0,0};
  f32x4 zA = {0,0,0,0}, zB = {0,0,0,0};
#pragma unroll 4
  for (int g = 0; g < HH; ++g) {
    f32x4 wu = *(const f32x4*)&Wul[g * HH + c4];
    f32x4 wm = *(const f32x4*)&Wml[g * HH + c4];
    f32x4 aA = sh_a[rg * 2][g];
    f32x4 aB = sh_a[rg * 2 + 1][g];
    hA += aA.x * wu; hB += aB.x * wu;
    xA += aA.y * wm; xB += aB.y * wm;
    yA += aA.z * wm; yB += aB.z * wm;
    zA += aA.w * wm; zB += aB.w * wm;
  }
  size_t rA = row0 + rg * 2, rB = rA + 1;
  f32x4 t;
  t = *(const f32x4*)&hin[rA * HH + c4]; t += hA; *(f32x4*)&hout[rA * HH + c4] = t;
  t = *(const f32x4*)&hin[rB * HH + c4]; t += hB; *(f32x4*)&hout[rB * HH + c4] = t;
  *(f32x4*)&v[(rA * 3 + 0) * HH + c4] = xA;
  *(f32x4*)&v[(rA * 3 + 1) * HH + c4] = yA;
  *(f32x4*)&v[(rA * 3 + 2) * HH + c4] = zA;
  *(f32x4*)&v[(rB * 3 + 0) * HH + c4] = xB;
  *(f32x4*)&v[(rB * 3 + 1) * HH + c4] = yB;
  *(f32x4*)&v[(rB * 3 + 2) * HH + c4] = zB;
}

// Layer-1 update fused with readout: h/v rows stay in LDS; g = silu(h@Wg1)@Wg2;
// out[n,d] = sum_c v[n,c,d]*g[n,c] * fs.  16 rows/block.
__global__ __launch_bounds__(256) void k_update_ro(
    const float* __restrict__ a0a1, const float* __restrict__ hin,
    const float* __restrict__ v,
    const float* __restrict__ Wul, const float* __restrict__ Wml,
    const float* __restrict__ Wg1, const float* __restrict__ Wg2,
    const float* __restrict__ fs, float* __restrict__ out) {
  __shared__ __align__(16) f32x4 sh_a[16][HH];    // 32 KB (aliased by q/g later)
  __shared__ float sh_h[16][HH];                  // 8 KB
  __shared__ float sh_v[16][3][132];              // 25.4 KB (+4 pad: contraction conflicts)
  float* sh_q = (float*)&sh_a[0][0];              // 8 KB  (aliases dead sh_a)
  float* sh_g = (float*)&sh_a[8][0];              // 8 KB
  int tid = threadIdx.x;
  int row0 = blockIdx.x * 16;
  const f32x4* src = (const f32x4*)(a0a1 + (size_t)row0 * HH * 4);
  for (int i = tid; i < 16 * HH; i += 256) sh_a[i >> 7][i & 127] = src[i];
  __syncthreads();
  {
    int c4 = (tid & 31) * 4;
    int rg = tid >> 5;
    f32x4 hA = {0,0,0,0}, hB = {0,0,0,0};
    f32x4 xA = {0,0,0,0}, xB = {0,0,0,0};
    f32x4 yA = {0,0,0,0}, yB = {0,0,0,0};
    f32x4 zA = {0,0,0,0}, zB = {0,0,0,0};
#pragma unroll 4
    for (int g = 0; g < HH; ++g) {
      f32x4 wu = *(const f32x4*)&Wul[g * HH + c4];
      f32x4 wm = *(const f32x4*)&Wml[g * HH + c4];
      f32x4 aA = sh_a[rg * 2][g];
      f32x4 aB = sh_a[rg * 2 + 1][g];
      hA += aA.x * wu; hB += aB.x * wu;
      xA += aA.y * wm; xB += aB.y * wm;
      yA += aA.z * wm; yB += aB.z * wm;
      zA += aA.w * wm; zB += aB.w * wm;
    }
    size_t rA = row0 + rg * 2, rB = rA + 1;
    int lrA = rg * 2, lrB = lrA + 1;
#pragma unroll
    for (int j = 0; j < 4; ++j) {
      sh_h[lrA][c4 + j] = hin[rA * HH + c4 + j] + hA[j];
      sh_h[lrB][c4 + j] = hin[rB * HH + c4 + j] + hB[j];
      sh_v[lrA][0][c4 + j] = v[(rA * 3 + 0) * HH + c4 + j] + xA[j];
      sh_v[lrA][1][c4 + j] = v[(rA * 3 + 1) * HH + c4 + j] + yA[j];
      sh_v[lrA][2][c4 + j] = v[(rA * 3 + 2) * HH + c4 + j] + zA[j];
      sh_v[lrB][0][c4 + j] = v[(rB * 3 + 0) * HH + c4 + j] + xB[j];
      sh_v[lrB][1][c4 + j] = v[(rB * 3 + 1) * HH + c4 + j] + yB[j];
      sh_v[lrB][2][c4 + j] = v[(rB * 3 + 2) * HH + c4 + j] + zB[j];
    }
  }
  __syncthreads();
  // gate GEMM 1: q = silu(h @ Wg1)   (8 rows per thread-half)
  {
    int c = tid & 127, r8 = (tid >> 7) * 8;
    float q[8] = {0,0,0,0,0,0,0,0};
#pragma unroll 4
    for (int k = 0; k < HH; ++k) {
      float wg = Wg1[k * HH + c];
#pragma unroll
      for (int j = 0; j < 8; ++j) q[j] += sh_h[r8 + j][k] * wg;
    }
#pragma unroll
    for (int j = 0; j < 8; ++j) sh_q[(r8 + j) * HH + c] = silu_f(q[j]);
  }
  __syncthreads();
  // gate GEMM 2: g = q @ Wg2
  {
    int c = tid & 127, r8 = (tid >> 7) * 8;
    float gg[8] = {0,0,0,0,0,0,0,0};
#pragma unroll 4
    for (int k = 0; k < HH; ++k) {
      float wg = Wg2[k * HH + c];
#pragma unroll
      for (int j = 0; j < 8; ++j) gg[j] += sh_q[(r8 + j) * HH + k] * wg;
    }
#pragma unroll
    for (int j = 0; j < 8; ++j) sh_g[(r8 + j) * HH + c] = gg[j];
  }
  __syncthreads();
  // contraction: out[row,d] = sum_c v[row][d][c]*g[row][c]; 16 lanes per row
  {
    int row = tid >> 4, i = tid & 15;
    float px = 0.f, py = 0.f, pz = 0.f;
#pragma unroll
    for (int t = 0; t < 8; ++t) {
      int cc = i + t * 16;
      float gv = sh_g[row * HH + cc];
      px += sh_v[row][0][cc] * gv;
      py += sh_v[row][1][cc] * gv;
      pz += sh_v[row][2][cc] * gv;
    }
#pragma unroll
    for (int off = 8; off > 0; off >>= 1) {
      px += __shfl_down(px, off);
      py += __shfl_down(py, off);
      pz += __shfl_down(pz, off);
    }
    if (i == 0) {
      float s = fs[0];
      size_t o = ((size_t)(row0 + row)) * 3;
      out[o + 0] = px * s; out[o + 1] = py * s; out[o + 2] = pz * s;
    }
  }
}

extern "C" void kernel_launch(void* const* d_in, const int* in_sizes, int n_in,
                              void* d_out, int out_size, void* d_ws, size_t ws_size,
                              hipStream_t stream) {
  const float* pos  = (const float*)d_in[0];
  const int*   z    = (const int*)d_in[1];
  const float* gf   = (const float*)d_in[2];
  const float* emb  = (const float*)d_in[3];
  const float* Wt   = (const float*)d_in[4];
  const float* Wr1  = (const float*)d_in[5];
  const float* Wr2  = (const float*)d_in[6];
  const float* Wupd = (const float*)d_in[7];
  const float* Wmix = (const float*)d_in[8];
  const float* Wg1  = (const float*)d_in[9];
  const float* Wg2  = (const float*)d_in[10];
  const float* fs   = (const float*)d_in[11];
  float* out = (float*)d_out;

  float* ws = (float*)d_ws;
  const size_t HN = (size_t)BB * NN * HH;   // 524288
  float* hA   = ws;                          // 2 MB
  float* hB   = ws + HN;                     // 2 MB
  float* v    = ws + 2 * HN;                 // 6 MB
  float* a0a1 = ws + 5 * HN;                 // 8 MB ([4096][128][4])
  unsigned short* Wr2p = (unsigned short*)(ws + 9 * HN);  // 64 KB

  k_init<<<dim3(BB), dim3(256), 0, stream>>>(emb, z, gf, Wt, Wr2, hA, Wr2p);
  k_layer<<<dim3(BB * NN), dim3(256), 0, stream>>>(pos, hA, a0a1, Wr1, Wr2p, 0);
  k_update<<<dim3(256), dim3(256), 0, stream>>>(a0a1, hA, hB, v, Wupd, Wmix);
  k_layer<<<dim3(BB * NN), dim3(256), 0, stream>>>(pos, hB, a0a1, Wr1, Wr2p, 1);
  k_update_ro<<<dim3(256), dim3(256), 0, stream>>>(a0a1, hB, v,
      Wupd + 16384, Wmix + 16384, Wg1, Wg2, fs, out);
}